// Round 4
// baseline (95.740 us; speedup 1.0000x reference)
//
#include <hip/hip_runtime.h>
#include <math.h>

#define BB 8
#define SS 2048
#define DD 1024
#define MM 4096
#define dd 256
#define NCH 64          // S-chunks for x column-sum
#define CS (SS/NCH)     // 32 rows per chunk

// ---- ws layout (floats) ----
#define OFF_PART  0                        // [b*64+chunk][256 float4] = 524288 floats
#define OFF_Q     524288                   // 2048
#define OFF_WV    526336                   // 2048
#define OFF_GATE  528384                   // 8
#define OFF_COMBO 528392                   // 8
#define OFF_SUMS  528400                   // 16
#define OFF_SC    528416                   // [which*8+b][m] = 65536
#define OFF_PRET  593952                   // [(b*64+mc)*256+j] = 131072
#define OFF_ROUT  725024                   // 8192

// K1: x partial column sums. grid = B*NCH = 512, block 256, float4/thread.
__global__ void k1(const float* __restrict__ x, float* __restrict__ ws) {
    int blk = blockIdx.x;
    int chunk = blk & 63;
    int b = blk >> 6;
    int t = threadIdx.x;
    const float4* x4 = (const float4*)(x + ((size_t)b*SS + (size_t)chunk*CS)*DD);
    float4 a = make_float4(0.f,0.f,0.f,0.f);
    #pragma unroll 8
    for (int s = 0; s < CS; ++s) {
        float4 v = x4[s*(DD/4) + t];
        a.x += v.x; a.y += v.y; a.z += v.z; a.w += v.w;
    }
    ((float4*)(ws + OFF_PART))[(size_t)(b*NCH + chunk)*256 + t] = a;
}

// K2: fused projections + gate. grid = 24 blocks, block 256.
//  blocks 0..15 (which=blk&1, b=blk>>1): xs[b] in LDS, full 1024-k matvec.
//  blocks 16..23 (b=blk-16): gate = sigmoid(mean(x[b]) . Wg + bg).
__global__ void k2(const float* __restrict__ Wq, const float* __restrict__ bq,
                   const float* __restrict__ Wv, const float* __restrict__ bv,
                   const float* __restrict__ Wg, const float* __restrict__ bg,
                   float* __restrict__ ws) {
    int blk = blockIdx.x;
    int t = threadIdx.x;
    const float4* p4 = (const float4*)(ws + OFF_PART);
    if (blk < 16) {
        __shared__ float4 xs4[256];
        int which = blk & 1;
        int b = blk >> 1;
        float4 a = make_float4(0.f,0.f,0.f,0.f);
        #pragma unroll 8
        for (int c = 0; c < NCH; ++c) {
            float4 v = p4[(size_t)(b*NCH + c)*256 + t];
            a.x += v.x; a.y += v.y; a.z += v.z; a.w += v.w;
        }
        xs4[t] = make_float4(a.x*(1.f/SS), a.y*(1.f/SS), a.z*(1.f/SS), a.w*(1.f/SS));
        __syncthreads();
        const float* xs = (const float*)xs4;
        const float* W = which ? Wv : Wq;
        float a0=0.f, a1=0.f, a2=0.f, a3=0.f;
        for (int k = 0; k < DD; k += 4) {
            a0 += xs[k]   * W[(size_t)k*dd + t];
            a1 += xs[k+1] * W[(size_t)(k+1)*dd + t];
            a2 += xs[k+2] * W[(size_t)(k+2)*dd + t];
            a3 += xs[k+3] * W[(size_t)(k+3)*dd + t];
        }
        float acc = (a0+a1) + (a2+a3) + (which ? bv[t] : bq[t]);
        ws[(which ? OFF_WV : OFF_Q) + b*dd + t] = acc;
    } else {
        __shared__ float red[256];
        int b = blk - 16;
        float4 wg = ((const float4*)Wg)[t];
        float acc = 0.f;
        #pragma unroll 8
        for (int c = 0; c < NCH; ++c) {
            float4 v = p4[(size_t)(b*NCH + c)*256 + t];
            acc += v.x*wg.x + v.y*wg.y + v.z*wg.z + v.w*wg.w;
        }
        red[t] = acc; __syncthreads();
        for (int s2 = 128; s2 > 0; s2 >>= 1) {
            if (t < s2) red[t] += red[t + s2];
            __syncthreads();
        }
        if (t == 0)
            ws[OFF_GATE + b] = 1.f / (1.f + __expf(-(red[0]*(1.f/SS) + bg[0])));
    }
}

// K4: scores -> exp. one wave per (which,b,m). grid = 2*B*M/4 = 16384, block 256.
__global__ void k4(const float* __restrict__ memory, float* __restrict__ ws) {
    int wave = threadIdx.x >> 6;
    int lane = threadIdx.x & 63;
    int task = blockIdx.x*4 + wave;
    int m = task & (MM-1);
    int b = (task >> 12) & 7;
    int which = task >> 15;
    const float* row = (which == 0) ? (memory + (size_t)m*dd)
                                    : (memory + ((size_t)b*MM + m)*dd);
    const float4 a  = ((const float4*)row)[lane];
    const float4 qv = ((const float4*)(ws + OFF_Q + b*dd))[lane];
    float p = a.x*qv.x + a.y*qv.y + a.z*qv.z + a.w*qv.w;
    #pragma unroll
    for (int off = 32; off > 0; off >>= 1) p += __shfl_xor(p, off);
    if (lane == 0) ws[OFF_SC + (size_t)(which*BB + b)*MM + m] = __expf(p);
}

// K5: blocks 0..15 row sums; blocks 16..527 retrieval partials (m-chunks of 64).
__global__ void k5(const float* __restrict__ memory, float* __restrict__ ws) {
    __shared__ float red[256];
    int blk = blockIdx.x;
    int t = threadIdx.x;
    if (blk < 16) {
        const float4* p = (const float4*)(ws + OFF_SC + (size_t)blk*MM);
        float s = 0.f;
        #pragma unroll
        for (int i = 0; i < 4; ++i) {
            float4 v = p[i*256 + t];
            s += v.x + v.y + v.z + v.w;
        }
        red[t] = s; __syncthreads();
        for (int s2 = 128; s2 > 0; s2 >>= 1) {
            if (t < s2) red[t] += red[t + s2];
            __syncthreads();
        }
        if (t == 0) ws[OFF_SUMS + blk] = red[0];
    } else {
        int idx = blk - 16;
        int mc = idx & 63;
        int b = idx >> 6;
        if (t < 64) red[t] = ws[OFF_SC + (size_t)b*MM + mc*64 + t];
        __syncthreads();
        float acc = 0.f;
        const float* pat = memory + (size_t)mc*64*dd + t;
        #pragma unroll 8
        for (int i = 0; i < 64; ++i) acc += red[i] * pat[(size_t)i*dd];
        ws[OFF_PRET + (size_t)(b*64 + mc)*dd + t] = acc;
    }
}

// K7: reduce PRET + normalize + Wo matvec + combo scalar. grid = B*16 = 128, block 256.
__global__ void k7(const float* __restrict__ Wo, const float* __restrict__ bo,
                   float* __restrict__ ws) {
    __shared__ float ret[dd];
    __shared__ float red[256];
    int blk = blockIdx.x;
    int cb = blk & 15;
    int b = blk >> 4;
    int t = threadIdx.x;
    float acc0 = 0.f;
    #pragma unroll 8
    for (int mc = 0; mc < 64; ++mc)
        acc0 += ws[OFF_PRET + (size_t)(b*64 + mc)*dd + t];
    ret[t] = acc0 / ws[OFF_SUMS + b];
    if (cb == 0 && t == 0)
        ws[OFF_COMBO + b] = 0.05f * ws[OFF_GATE + b] / ws[OFF_SUMS + BB + b];
    __syncthreads();
    int c = t & 63, jr = t >> 6;
    float acc = 0.f;
    #pragma unroll 8
    for (int jj = 0; jj < 64; ++jj) {
        int j = jr*64 + jj;
        acc += ret[j] * Wo[(size_t)j*DD + cb*64 + c];
    }
    red[t] = acc; __syncthreads();
    if (t < 64) {
        ws[OFF_ROUT + (size_t)b*DD + cb*64 + t] =
            red[t] + red[t+64] + red[t+128] + red[t+192] + bo[cb*64 + t];
    }
}

// K8: fused elementwise outputs. float4 grid-stride, grid 4096.
__global__ void k8(const float* __restrict__ x, const float* __restrict__ memory,
                   const float* __restrict__ ws, float* __restrict__ out) {
    const int NA = BB*SS*DD/4;       // 4194304
    const int NT = NA + BB*MM*dd/4;  // 6291456
    const float4* x4 = (const float4*)x;
    const float4* m4 = (const float4*)memory;
    const float4* r4 = (const float4*)(ws + OFF_ROUT);
    const float4* w4 = (const float4*)(ws + OFF_WV);
    float4* o4 = (float4*)out;
    int stride = gridDim.x * blockDim.x;
    for (int i = blockIdx.x*blockDim.x + threadIdx.x; i < NT; i += stride) {
        if (i < NA) {
            int b = i >> 19;
            int c = i & 255;
            float4 xv = x4[i];
            float4 rv = r4[(b << 8) + c];
            o4[i] = make_float4(xv.x+rv.x, xv.y+rv.y, xv.z+rv.z, xv.w+rv.w);
        } else {
            int j = i - NA;
            int b = j >> 18;
            int m = (j >> 6) & (MM-1);
            int d4 = j & 63;
            float coeff = ws[OFF_COMBO + b] * ws[OFF_SC + (size_t)(BB + b)*MM + m];
            float4 wv = w4[(b << 6) + d4];
            float4 mv = m4[j];
            o4[i] = make_float4(0.95f*mv.x + coeff*wv.x,
                                0.95f*mv.y + coeff*wv.y,
                                0.95f*mv.z + coeff*wv.z,
                                0.95f*mv.w + coeff*wv.w);
        }
    }
}

extern "C" void kernel_launch(void* const* d_in, const int* in_sizes, int n_in,
                              void* d_out, int out_size, void* d_ws, size_t ws_size,
                              hipStream_t stream) {
    const float* x      = (const float*)d_in[0];
    const float* memory = (const float*)d_in[1];
    const float* Wq     = (const float*)d_in[2];
    const float* bq     = (const float*)d_in[3];
    const float* Wv     = (const float*)d_in[4];
    const float* bv     = (const float*)d_in[5];
    const float* Wo     = (const float*)d_in[6];
    const float* bo     = (const float*)d_in[7];
    const float* Wg     = (const float*)d_in[8];
    const float* bg     = (const float*)d_in[9];
    float* out = (float*)d_out;
    float* ws  = (float*)d_ws;

    k1<<<BB*NCH, 256, 0, stream>>>(x, ws);
    k2<<<24, 256, 0, stream>>>(Wq, bq, Wv, bv, Wg, bg, ws);
    k4<<<2*BB*MM/4, 256, 0, stream>>>(memory, ws);
    k5<<<16 + BB*64, 256, 0, stream>>>(memory, ws);
    k7<<<BB*16, 256, 0, stream>>>(Wo, bo, ws);
    k8<<<4096, 256, 0, stream>>>(x, memory, ws, out);
}

// Round 5
// 76.758 us; speedup vs baseline: 1.2473x; 1.2473x over previous
//
#include <hip/hip_runtime.h>
#include <math.h>

#define BB 8
#define SS 2048
#define DD 1024
#define MM 4096
#define dd 256
#define NCH 64          // S-chunks for x column-sum
#define CS (SS/NCH)     // 32 rows per chunk

// ---- ws layout (floats) ----
#define OFF_PART  0                        // [b*64+chunk][1024] = 524288 floats
#define OFF_Q     524288                   // 2048
#define OFF_WV    526336                   // 2048
#define OFF_GATE  528384                   // 8
#define OFF_COMBO 528392                   // 8
#define OFF_SUMS  528400                   // 16
#define OFF_SC    528416                   // [which*8+b][m] = 65536
#define OFF_PRET  593952                   // [(b*64+mc)*256+j] = 131072
#define OFF_ROUT  725024                   // 8192

// K1: x partial column sums. grid = B*NCH = 512, block 256, float4/thread.
__global__ void k1(const float* __restrict__ x, float* __restrict__ ws) {
    int blk = blockIdx.x;
    int chunk = blk & 63;
    int b = blk >> 6;
    int t = threadIdx.x;
    const float4* x4 = (const float4*)(x + ((size_t)b*SS + (size_t)chunk*CS)*DD);
    float4 a = make_float4(0.f,0.f,0.f,0.f);
    #pragma unroll 8
    for (int s = 0; s < CS; ++s) {
        float4 v = x4[s*(DD/4) + t];
        a.x += v.x; a.y += v.y; a.z += v.z; a.w += v.w;
    }
    ((float4*)(ws + OFF_PART))[(size_t)(b*NCH + chunk)*256 + t] = a;
}

// K23: fused projections + gate. grid = 72 blocks, block 512.
//  blocks 0..63: id = (which*8+b)*4+cs -> 64 output cols [cs*64, cs*64+64).
//    wave w = k-group (8 x 128 k's), lanes = 64 consecutive cols (coalesced).
//  blocks 64..71: gate for b = blk-64.
__global__ void k23(const float* __restrict__ Wq, const float* __restrict__ bq,
                    const float* __restrict__ Wv, const float* __restrict__ bv,
                    const float* __restrict__ Wg, const float* __restrict__ bg,
                    float* __restrict__ ws) {
    __shared__ float4 xsA[256];
    __shared__ float4 xsB[256];
    __shared__ float red[512];
    int blk = blockIdx.x;
    int t = threadIdx.x;
    if (blk < 64) {
        int cs = blk & 3;
        int wb = blk >> 2;          // which*8 + b
        int b = wb & 7;
        int which = wb >> 3;
        // phase 1: xs[b] (mean over S) from PART, 512 threads, 2 chunk-halves
        int col4 = t & 255;
        int half = t >> 8;
        const float4* p4 = (const float4*)(ws + OFF_PART);
        float4 a = make_float4(0.f,0.f,0.f,0.f);
        #pragma unroll 8
        for (int c = 0; c < 32; ++c) {
            float4 v = p4[(size_t)(b*NCH + half*32 + c)*256 + col4];
            a.x += v.x; a.y += v.y; a.z += v.z; a.w += v.w;
        }
        if (half == 0) xsA[col4] = a; else xsB[col4] = a;
        __syncthreads();
        if (t < 256) {
            float4 u = xsA[t], v = xsB[t];
            xsA[t] = make_float4((u.x+v.x)*(1.f/SS), (u.y+v.y)*(1.f/SS),
                                 (u.z+v.z)*(1.f/SS), (u.w+v.w)*(1.f/SS));
        }
        __syncthreads();
        const float* xs = (const float*)xsA;
        // phase 2: matvec slice; wave = k-group, lane = col
        const float* W = which ? Wv : Wq;
        int kg = t >> 6;
        int c0 = cs*64 + (t & 63);
        float acc = 0.f;
        #pragma unroll 8
        for (int kk = 0; kk < 128; ++kk) {
            int k = kg*128 + kk;
            acc += xs[k] * W[(size_t)k*dd + c0];
        }
        red[t] = acc;
        __syncthreads();
        if (t < 64) {
            int c = cs*64 + t;
            float o = red[t] + red[t+64] + red[t+128] + red[t+192]
                    + red[t+256] + red[t+320] + red[t+384] + red[t+448];
            o += which ? bv[c] : bq[c];
            ws[(which ? OFF_WV : OFF_Q) + b*dd + c] = o;
        }
    } else {
        int b = blk - 64;
        const float* base = ws + OFF_PART + (size_t)(b*NCH)*DD;
        float wg0 = Wg[t], wg1 = Wg[t + 512];
        float acc = 0.f;
        #pragma unroll 8
        for (int c = 0; c < NCH; ++c) {
            const float* p = base + (size_t)c*DD;
            acc += p[t]*wg0 + p[t+512]*wg1;
        }
        red[t] = acc; __syncthreads();
        for (int s2 = 256; s2 > 0; s2 >>= 1) {
            if (t < s2) red[t] += red[t + s2];
            __syncthreads();
        }
        if (t == 0)
            ws[OFF_GATE + b] = 1.f / (1.f + __expf(-(red[0]*(1.f/SS) + bg[0])));
    }
}

// K4: scores -> exp. one wave per (which,b,m). grid = 2*B*M/4 = 16384, block 256.
__global__ void k4(const float* __restrict__ memory, float* __restrict__ ws) {
    int wave = threadIdx.x >> 6;
    int lane = threadIdx.x & 63;
    int task = blockIdx.x*4 + wave;
    int m = task & (MM-1);
    int b = (task >> 12) & 7;
    int which = task >> 15;
    const float* row = (which == 0) ? (memory + (size_t)m*dd)
                                    : (memory + ((size_t)b*MM + m)*dd);
    const float4 a  = ((const float4*)row)[lane];
    const float4 qv = ((const float4*)(ws + OFF_Q + b*dd))[lane];
    float p = a.x*qv.x + a.y*qv.y + a.z*qv.z + a.w*qv.w;
    #pragma unroll
    for (int off = 32; off > 0; off >>= 1) p += __shfl_xor(p, off);
    if (lane == 0) ws[OFF_SC + (size_t)(which*BB + b)*MM + m] = __expf(p);
}

// K5: blocks 0..15 row sums; blocks 16..527 retrieval partials (m-chunks of 64).
__global__ void k5(const float* __restrict__ memory, float* __restrict__ ws) {
    __shared__ float red[256];
    int blk = blockIdx.x;
    int t = threadIdx.x;
    if (blk < 16) {
        const float4* p = (const float4*)(ws + OFF_SC + (size_t)blk*MM);
        float s = 0.f;
        #pragma unroll
        for (int i = 0; i < 4; ++i) {
            float4 v = p[i*256 + t];
            s += v.x + v.y + v.z + v.w;
        }
        red[t] = s; __syncthreads();
        for (int s2 = 128; s2 > 0; s2 >>= 1) {
            if (t < s2) red[t] += red[t + s2];
            __syncthreads();
        }
        if (t == 0) ws[OFF_SUMS + blk] = red[0];
    } else {
        int idx = blk - 16;
        int mc = idx & 63;
        int b = idx >> 6;
        if (t < 64) red[t] = ws[OFF_SC + (size_t)b*MM + mc*64 + t];
        __syncthreads();
        float acc = 0.f;
        const float* pat = memory + (size_t)mc*64*dd + t;
        #pragma unroll 8
        for (int i = 0; i < 64; ++i) acc += red[i] * pat[(size_t)i*dd];
        ws[OFF_PRET + (size_t)(b*64 + mc)*dd + t] = acc;
    }
}

// K7: reduce PRET + normalize + Wo matvec + combo scalar. grid = B*16 = 128, block 256.
__global__ void k7(const float* __restrict__ Wo, const float* __restrict__ bo,
                   float* __restrict__ ws) {
    __shared__ float ret[dd];
    __shared__ float red[256];
    int blk = blockIdx.x;
    int cb = blk & 15;
    int b = blk >> 4;
    int t = threadIdx.x;
    float acc0 = 0.f;
    #pragma unroll 8
    for (int mc = 0; mc < 64; ++mc)
        acc0 += ws[OFF_PRET + (size_t)(b*64 + mc)*dd + t];
    ret[t] = acc0 / ws[OFF_SUMS + b];
    if (cb == 0 && t == 0)
        ws[OFF_COMBO + b] = 0.05f * ws[OFF_GATE + b] / ws[OFF_SUMS + BB + b];
    __syncthreads();
    int c = t & 63, jr = t >> 6;
    float acc = 0.f;
    #pragma unroll 8
    for (int jj = 0; jj < 64; ++jj) {
        int j = jr*64 + jj;
        acc += ret[j] * Wo[(size_t)j*DD + cb*64 + c];
    }
    red[t] = acc; __syncthreads();
    if (t < 64) {
        ws[OFF_ROUT + (size_t)b*DD + cb*64 + t] =
            red[t] + red[t+64] + red[t+128] + red[t+192] + bo[cb*64 + t];
    }
}

// K8: fused elementwise outputs. float4 grid-stride, grid 4096.
__global__ void k8(const float* __restrict__ x, const float* __restrict__ memory,
                   const float* __restrict__ ws, float* __restrict__ out) {
    const int NA = BB*SS*DD/4;       // 4194304
    const int NT = NA + BB*MM*dd/4;  // 6291456
    const float4* x4 = (const float4*)x;
    const float4* m4 = (const float4*)memory;
    const float4* r4 = (const float4*)(ws + OFF_ROUT);
    const float4* w4 = (const float4*)(ws + OFF_WV);
    float4* o4 = (float4*)out;
    int stride = gridDim.x * blockDim.x;
    for (int i = blockIdx.x*blockDim.x + threadIdx.x; i < NT; i += stride) {
        if (i < NA) {
            int b = i >> 19;
            int c = i & 255;
            float4 xv = x4[i];
            float4 rv = r4[(b << 8) + c];
            o4[i] = make_float4(xv.x+rv.x, xv.y+rv.y, xv.z+rv.z, xv.w+rv.w);
        } else {
            int j = i - NA;
            int b = j >> 18;
            int m = (j >> 6) & (MM-1);
            int d4 = j & 63;
            float coeff = ws[OFF_COMBO + b] * ws[OFF_SC + (size_t)(BB + b)*MM + m];
            float4 wv = w4[(b << 6) + d4];
            float4 mv = m4[j];
            o4[i] = make_float4(0.95f*mv.x + coeff*wv.x,
                                0.95f*mv.y + coeff*wv.y,
                                0.95f*mv.z + coeff*wv.z,
                                0.95f*mv.w + coeff*wv.w);
        }
    }
}

extern "C" void kernel_launch(void* const* d_in, const int* in_sizes, int n_in,
                              void* d_out, int out_size, void* d_ws, size_t ws_size,
                              hipStream_t stream) {
    const float* x      = (const float*)d_in[0];
    const float* memory = (const float*)d_in[1];
    const float* Wq     = (const float*)d_in[2];
    const float* bq     = (const float*)d_in[3];
    const float* Wv     = (const float*)d_in[4];
    const float* bv     = (const float*)d_in[5];
    const float* Wo     = (const float*)d_in[6];
    const float* bo     = (const float*)d_in[7];
    const float* Wg     = (const float*)d_in[8];
    const float* bg     = (const float*)d_in[9];
    float* out = (float*)d_out;
    float* ws  = (float*)d_ws;

    k1<<<BB*NCH, 256, 0, stream>>>(x, ws);
    k23<<<72, 512, 0, stream>>>(Wq, bq, Wv, bv, Wg, bg, ws);
    k4<<<2*BB*MM/4, 256, 0, stream>>>(memory, ws);
    k5<<<16 + BB*64, 256, 0, stream>>>(memory, ws);
    k7<<<BB*16, 256, 0, stream>>>(Wo, bo, ws);
    k8<<<4096, 256, 0, stream>>>(x, memory, ws, out);
}

// Round 6
// 73.801 us; speedup vs baseline: 1.2973x; 1.0401x over previous
//
#include <hip/hip_runtime.h>
#include <math.h>

#define BB 8
#define SS 2048
#define DD 1024
#define MM 4096
#define dd 256
#define NCH 64          // S-chunks for x column-sum
#define CS (SS/NCH)     // 32 rows per chunk

// ---- ws layout (floats) ----
#define OFF_PART  0                        // [b*64+chunk][1024] = 524288
#define OFF_Q     524288                   // 2048
#define OFF_WV    526336                   // 2048
#define OFF_GATE  528384                   // 8
#define OFF_COMBO 528392                   // 8
#define OFF_SUMP  528400                   // [which*512 + b*64 + mc] = 1024
#define OFF_SC    529424                   // write-side exp scores [b][m] = 32768
#define OFF_PRET  562192                   // [(b*64+mc)*256+j] = 131072
#define OFF_ROUT  693264                   // 8192

// K1: x partial column sums. grid = B*NCH = 512, block 256, float4/thread.
__global__ void k1(const float* __restrict__ x, float* __restrict__ ws) {
    int blk = blockIdx.x;
    int chunk = blk & 63;
    int b = blk >> 6;
    int t = threadIdx.x;
    const float4* x4 = (const float4*)(x + ((size_t)b*SS + (size_t)chunk*CS)*DD);
    float4 a = make_float4(0.f,0.f,0.f,0.f);
    #pragma unroll 8
    for (int s = 0; s < CS; ++s) {
        float4 v = x4[s*(DD/4) + t];
        a.x += v.x; a.y += v.y; a.z += v.z; a.w += v.w;
    }
    ((float4*)(ws + OFF_PART))[(size_t)(b*NCH + chunk)*256 + t] = a;
}

// K23: fused projections + gate. grid = 72 blocks, block 512. (unchanged from R5)
__global__ void k23(const float* __restrict__ Wq, const float* __restrict__ bq,
                    const float* __restrict__ Wv, const float* __restrict__ bv,
                    const float* __restrict__ Wg, const float* __restrict__ bg,
                    float* __restrict__ ws) {
    __shared__ float4 xsA[256];
    __shared__ float4 xsB[256];
    __shared__ float red[512];
    int blk = blockIdx.x;
    int t = threadIdx.x;
    const float4* p4 = (const float4*)(ws + OFF_PART);
    if (blk < 64) {
        int cs = blk & 3;
        int wb = blk >> 2;
        int b = wb & 7;
        int which = wb >> 3;
        int col4 = t & 255;
        int half = t >> 8;
        float4 a = make_float4(0.f,0.f,0.f,0.f);
        #pragma unroll 8
        for (int c = 0; c < 32; ++c) {
            float4 v = p4[(size_t)(b*NCH + half*32 + c)*256 + col4];
            a.x += v.x; a.y += v.y; a.z += v.z; a.w += v.w;
        }
        if (half == 0) xsA[col4] = a; else xsB[col4] = a;
        __syncthreads();
        if (t < 256) {
            float4 u = xsA[t], v = xsB[t];
            xsA[t] = make_float4((u.x+v.x)*(1.f/SS), (u.y+v.y)*(1.f/SS),
                                 (u.z+v.z)*(1.f/SS), (u.w+v.w)*(1.f/SS));
        }
        __syncthreads();
        const float* xs = (const float*)xsA;
        const float* W = which ? Wv : Wq;
        int kg = t >> 6;
        int c0 = cs*64 + (t & 63);
        float acc = 0.f;
        #pragma unroll 8
        for (int kk = 0; kk < 128; ++kk) {
            int k = kg*128 + kk;
            acc += xs[k] * W[(size_t)k*dd + c0];
        }
        red[t] = acc;
        __syncthreads();
        if (t < 64) {
            int c = cs*64 + t;
            float o = red[t] + red[t+64] + red[t+128] + red[t+192]
                    + red[t+256] + red[t+320] + red[t+384] + red[t+448];
            o += which ? bv[c] : bq[c];
            ws[(which ? OFF_WV : OFF_Q) + b*dd + c] = o;
        }
    } else {
        int b = blk - 64;
        const float* base = ws + OFF_PART + (size_t)(b*NCH)*DD;
        float wg0 = Wg[t], wg1 = Wg[t + 512];
        float acc = 0.f;
        #pragma unroll 8
        for (int c = 0; c < NCH; ++c) {
            const float* p = base + (size_t)c*DD;
            acc += p[t]*wg0 + p[t+512]*wg1;
        }
        red[t] = acc; __syncthreads();
        for (int s2 = 256; s2 > 0; s2 >>= 1) {
            if (t < s2) red[t] += red[t + s2];
            __syncthreads();
        }
        if (t == 0)
            ws[OFF_GATE + b] = 1.f / (1.f + __expf(-(red[0]*(1.f/SS) + bg[0])));
    }
}

// K45: fused scores+exp+rowsum-partial+retrieval-partial.
// grid = 1024: which = blk>>9, b = (blk>>6)&7, mc = blk&63 (64 m-rows per block).
__global__ void k45(const float* __restrict__ memory, float* __restrict__ ws) {
    __shared__ float esc[64];
    int idx = blockIdx.x;
    int which = idx >> 9;
    int b = (idx >> 6) & 7;
    int mc = idx & 63;
    int t = threadIdx.x;
    int wave = t >> 6, lane = t & 63;
    const float* tile = ((which == 0) ? memory : memory + (size_t)b*MM*dd)
                        + (size_t)mc*64*dd;
    const float4 qv = ((const float4*)(ws + OFF_Q + b*dd))[lane];
    // 64 dot products: wave w handles rows 4i+w, 16 rows serially
    #pragma unroll 4
    for (int i = 0; i < 16; ++i) {
        int r = i*4 + wave;
        float4 a = ((const float4*)(tile + (size_t)r*dd))[lane];
        float p = a.x*qv.x + a.y*qv.y + a.z*qv.z + a.w*qv.w;
        #pragma unroll
        for (int off = 32; off > 0; off >>= 1) p += __shfl_xor(p, off);
        if (lane == 0) esc[r] = __expf(p);
    }
    __syncthreads();
    if (t < 64) {
        float v = esc[t];
        #pragma unroll
        for (int off = 32; off > 0; off >>= 1) v += __shfl_xor(v, off);
        if (t == 0) ws[OFF_SUMP + which*512 + b*64 + mc] = v;
    }
    if (which == 0) {
        // partial retrieval over the L2-hot tile: thread t = output col
        float acc = 0.f;
        #pragma unroll 8
        for (int i = 0; i < 64; ++i) acc += esc[i] * tile[(size_t)i*dd + t];
        ws[OFF_PRET + (size_t)(b*64 + mc)*dd + t] = acc;
    } else {
        if (t < 64) ws[OFF_SC + (size_t)b*MM + mc*64 + t] = esc[t];
    }
}

// K7: SUMP reduce + PRET reduce + normalize + Wo matvec + combo. grid = 128, block 256.
__global__ void k7(const float* __restrict__ Wo, const float* __restrict__ bo,
                   float* __restrict__ ws) {
    __shared__ float ret[dd];
    __shared__ float red[256];
    __shared__ float ssum;
    int blk = blockIdx.x;
    int cb = blk & 15;
    int b = blk >> 4;
    int t = threadIdx.x;
    if (t < 64) {
        float v = ws[OFF_SUMP + b*64 + t];
        #pragma unroll
        for (int off = 32; off > 0; off >>= 1) v += __shfl_xor(v, off);
        if (t == 0) ssum = v;
    } else if (t < 128 && cb == 0) {
        float v = ws[OFF_SUMP + 512 + b*64 + (t - 64)];
        #pragma unroll
        for (int off = 32; off > 0; off >>= 1) v += __shfl_xor(v, off);
        if (t == 64) ws[OFF_COMBO + b] = 0.05f * ws[OFF_GATE + b] / v;
    }
    float acc0 = 0.f;
    #pragma unroll 8
    for (int mc = 0; mc < 64; ++mc)
        acc0 += ws[OFF_PRET + (size_t)(b*64 + mc)*dd + t];
    __syncthreads();
    ret[t] = acc0 / ssum;
    __syncthreads();
    int c = t & 63, jr = t >> 6;
    float acc = 0.f;
    #pragma unroll 8
    for (int jj = 0; jj < 64; ++jj) {
        int j = jr*64 + jj;
        acc += ret[j] * Wo[(size_t)j*DD + cb*64 + c];
    }
    red[t] = acc; __syncthreads();
    if (t < 64) {
        ws[OFF_ROUT + (size_t)b*DD + cb*64 + t] =
            red[t] + red[t+64] + red[t+128] + red[t+192] + bo[cb*64 + t];
    }
}

// K8: fused elementwise outputs. float4 grid-stride, grid 4096.
__global__ void k8(const float* __restrict__ x, const float* __restrict__ memory,
                   const float* __restrict__ ws, float* __restrict__ out) {
    const int NA = BB*SS*DD/4;       // 4194304
    const int NT = NA + BB*MM*dd/4;  // 6291456
    const float4* x4 = (const float4*)x;
    const float4* m4 = (const float4*)memory;
    const float4* r4 = (const float4*)(ws + OFF_ROUT);
    const float4* w4 = (const float4*)(ws + OFF_WV);
    float4* o4 = (float4*)out;
    int stride = gridDim.x * blockDim.x;
    for (int i = blockIdx.x*blockDim.x + threadIdx.x; i < NT; i += stride) {
        if (i < NA) {
            int b = i >> 19;
            int c = i & 255;
            float4 xv = x4[i];
            float4 rv = r4[(b << 8) + c];
            o4[i] = make_float4(xv.x+rv.x, xv.y+rv.y, xv.z+rv.z, xv.w+rv.w);
        } else {
            int j = i - NA;
            int b = j >> 18;
            int m = (j >> 6) & (MM-1);
            int d4 = j & 63;
            float coeff = ws[OFF_COMBO + b] * ws[OFF_SC + (size_t)b*MM + m];
            float4 wv = w4[(b << 6) + d4];
            float4 mv = m4[j];
            o4[i] = make_float4(0.95f*mv.x + coeff*wv.x,
                                0.95f*mv.y + coeff*wv.y,
                                0.95f*mv.z + coeff*wv.z,
                                0.95f*mv.w + coeff*wv.w);
        }
    }
}

extern "C" void kernel_launch(void* const* d_in, const int* in_sizes, int n_in,
                              void* d_out, int out_size, void* d_ws, size_t ws_size,
                              hipStream_t stream) {
    const float* x      = (const float*)d_in[0];
    const float* memory = (const float*)d_in[1];
    const float* Wq     = (const float*)d_in[2];
    const float* bq     = (const float*)d_in[3];
    const float* Wv     = (const float*)d_in[4];
    const float* bv     = (const float*)d_in[5];
    const float* Wo     = (const float*)d_in[6];
    const float* bo     = (const float*)d_in[7];
    const float* Wg     = (const float*)d_in[8];
    const float* bg     = (const float*)d_in[9];
    float* out = (float*)d_out;
    float* ws  = (float*)d_ws;

    k1<<<BB*NCH, 256, 0, stream>>>(x, ws);
    k23<<<72, 512, 0, stream>>>(Wq, bq, Wv, bv, Wg, bg, ws);
    k45<<<1024, 256, 0, stream>>>(memory, ws);
    k7<<<BB*16, 256, 0, stream>>>(Wo, bo, ws);
    k8<<<4096, 256, 0, stream>>>(x, memory, ws, out);
}